// Round 13
// baseline (91.074 us; speedup 1.0000x reference)
//
#include <hip/hip_runtime.h>
#include <math.h>

#define LSEQ 512
#define DMODEL 512
#define DT 64
#define DFF 2048

typedef unsigned short u16;
typedef __attribute__((ext_vector_type(8))) short short8;
typedef __attribute__((ext_vector_type(4))) float f32x4;

__device__ __forceinline__ float wave_sum(float v) {
#pragma unroll
  for (int o = 32; o > 0; o >>= 1) v += __shfl_xor(v, o, 64);
  return v;
}

__device__ __forceinline__ u16 f2bf(float f) {
  unsigned int u = __float_as_uint(f);
  u += 0x7fffu + ((u >> 16) & 1u);
  return (u16)(u >> 16);
}
__device__ __forceinline__ float bf2f(u16 h) {
  return __uint_as_float(((unsigned int)h) << 16);
}
__device__ __forceinline__ void splitbf(float f, u16& h, u16& l) {
  h = f2bf(f);
  l = f2bf(f - bf2f(h));
}
// load 8 fp32 and split into hi/lo bf16 fragments
__device__ __forceinline__ void split8(const float* __restrict__ p,
                                       short8& bh, short8& bl) {
  float4 a = *(const float4*)p;
  float4 b = *(const float4*)(p + 4);
  float vv[8] = {a.x, a.y, a.z, a.w, b.x, b.y, b.z, b.w};
#pragma unroll
  for (int e = 0; e < 8; ++e) {
    u16 h, l; splitbf(vv[e], h, l);
    bh[e] = (short)h; bl[e] = (short)l;
  }
}

// 16x16x32-fragment-ready layout for matrix X[R][C] (R = out-cols, C = K):
//   tile t = r/16, kb = c/32, lane = (r%16) + 16*((c%32)/8), e = c%8
//   flat(u16) = t*(C*16) + kb*512 + lane*8 + e
// Wave fragment load (tile t, kb): &X'[t*(C*16) + kb*512 + lane*8]  -> coalesced 1KB.

// ---------------- k_fa: blocks 0..63: LN1 + proj(fc+lin_in bf16x3) + au + a-map ------
//                  blocks 64..319: w1/w2 -> swizzled bf16 (16x16-frag layout)
__global__ __launch_bounds__(512) void k_fa(
    const float* __restrict__ x, const float* __restrict__ g1,
    const float* __restrict__ be1,
    const float* __restrict__ fcw, const float* __restrict__ liw,
    const float* __restrict__ wa,
    const float* __restrict__ fcb, const float* __restrict__ lib,
    const float* __restrict__ w1, const float* __restrict__ w2,
    float* __restrict__ y_o, float* __restrict__ u_o,
    float* __restrict__ ar_o, float* __restrict__ ai_o,
    u16* __restrict__ w1s, u16* __restrict__ w2s)
{
  const int blk = blockIdx.x;
  if (blk >= 64) {                           // ---- w1/w2 -> 16x16-frag swizzle ----
    for (int i = (blk - 64) * 512 + threadIdx.x; i < 524288; i += 131072) {
      if (i < 262144) {                      // w1 (2048 x 512)
        int r = i >> 7, c0 = (i & 127) << 2;
        float4 v = ((const float4*)w1)[i];
        ushort4 o;
        o.x = f2bf(v.x); o.y = f2bf(v.y); o.z = f2bf(v.z); o.w = f2bf(v.w);
        int flat = (r >> 4) * 8192 + (c0 >> 5) * 512 +
                   ((r & 15) + 16 * ((c0 & 31) >> 3)) * 8 + (c0 & 7);
        *(ushort4*)(w1s + flat) = o;
      } else {                               // w2 (512 x 2048)
        int ii = i - 262144;
        int r = ii >> 9, c0 = (ii & 511) << 2;
        float4 v = ((const float4*)w2)[ii];
        ushort4 o;
        o.x = f2bf(v.x); o.y = f2bf(v.y); o.z = f2bf(v.z); o.w = f2bf(v.w);
        int flat = (r >> 4) * 32768 + (c0 >> 5) * 512 +
                   ((r & 15) + 16 * ((c0 & 31) >> 3)) * 8 + (c0 & 7);
        *(ushort4*)(w2s + flat) = o;
      }
    }
    return;
  }
  // ---- compute blocks: 16-row tile mt ----
  __shared__ __align__(16) u16 xsh[16][520];
  __shared__ __align__(16) u16 xsl[16][520];
  __shared__ __align__(16) u16 ush[16][80];
  __shared__ __align__(16) u16 usl[16][80];
  const int tid = threadIdx.x;
  const int wv = tid >> 6, lane = tid & 63;
  const int lr = lane & 15, lk = lane >> 4;
  const int mt = blk;

#pragma unroll
  for (int rr = 0; rr < 2; ++rr) {           // LN1, 16 rows
    const int r = wv * 2 + rr;
    const int row = mt * 16 + r;
    const float* xr = x + (size_t)row * DMODEL;
    float v[8]; float s = 0.f;
#pragma unroll
    for (int j = 0; j < 8; ++j) { v[j] = xr[lane + 64 * j]; s += v[j]; }
    s = wave_sum(s);
    const float mu = s * (1.f / 512.f);
    float q = 0.f;
#pragma unroll
    for (int j = 0; j < 8; ++j) { float dd = v[j] - mu; q += dd * dd; }
    q = wave_sum(q);
    const float rstd = rsqrtf(q * (1.f / 512.f) + 1e-5f);
#pragma unroll
    for (int j = 0; j < 8; ++j) {
      int idx = lane + 64 * j;
      float o = (v[j] - mu) * rstd * g1[idx] + be1[idx];
      u16 h, l; splitbf(o, h, l);
      xsh[r][idx] = h;
      xsl[r][idx] = l;
    }
  }
  __syncthreads();

  const int c = wv * 16 + lr;
  {  // proj tile, K=512, bf16x3; B fp32 split on the fly
    const float* brow = (c < DT) ? (fcw + (size_t)c * DMODEL)
                                 : (liw + (size_t)(c - DT) * DMODEL);
    f32x4 acc = {};
#pragma unroll 4
    for (int k = 0; k < DMODEL; k += 32) {
      short8 ah = *(const short8*)&xsh[lr][k + lk * 8];
      short8 al = *(const short8*)&xsl[lr][k + lk * 8];
      short8 bh, bl;
      split8(brow + k + lk * 8, bh, bl);
      acc = __builtin_amdgcn_mfma_f32_16x16x32_bf16(ah, bh, acc, 0, 0, 0);
      acc = __builtin_amdgcn_mfma_f32_16x16x32_bf16(ah, bl, acc, 0, 0, 0);
      acc = __builtin_amdgcn_mfma_f32_16x16x32_bf16(al, bh, acc, 0, 0, 0);
    }
#pragma unroll
    for (int j = 0; j < 4; ++j) {
      int rl = lk * 4 + j;
      int row = mt * 16 + rl;
      float v = acc[j];
      if (c < DT) {
        v += fcb[c];
        y_o[row * DT + c] = v / (1.f + expf(-v));        // silu gate (fp32)
      } else {
        int d = c - DT;
        v += lib[d];
        u_o[row * DT + d] = v;                           // fp32 for scan
        u16 h, l; splitbf(v, h, l);
        ush[rl][d] = h; usl[rl][d] = l;
      }
    }
  }
  __syncthreads();
  {  // au tile nt=wv over K=64, bf16x3; then a-map
    const float* warow = wa + (size_t)c * DT;
    f32x4 acc = {};
#pragma unroll
    for (int ks = 0; ks < 2; ++ks) {
      short8 ah = *(const short8*)&ush[lr][ks * 32 + lk * 8];
      short8 al = *(const short8*)&usl[lr][ks * 32 + lk * 8];
      short8 bh, bl;
      split8(warow + ks * 32 + lk * 8, bh, bl);
      acc = __builtin_amdgcn_mfma_f32_16x16x32_bf16(ah, bh, acc, 0, 0, 0);
      acc = __builtin_amdgcn_mfma_f32_16x16x32_bf16(ah, bl, acc, 0, 0, 0);
      acc = __builtin_amdgcn_mfma_f32_16x16x32_bf16(al, bh, acc, 0, 0, 0);
    }
#pragma unroll
    for (int j = 0; j < 4; ++j) {
      float v = acc[j];
      float p = __shfl_xor(v, 1, 64);
      float re = (lane & 1) ? p : v;
      float im = (lane & 1) ? v : p;
      float asq = re * re + im * im;
      float sc = rsqrtf(asq) * expf(-asq);
      int row = mt * 16 + lk * 4 + j;
      int d = c >> 1;
      if (lane & 1) ai_o[row * DT + d] = im * sc;
      else          ar_o[row * DT + d] = re * sc;
    }
  }
}

// ---------------- parallel backward affine scan (unchanged) --------------------------
__global__ __launch_bounds__(64) void k_scan2(
    const float* __restrict__ u, const float* __restrict__ ar, const float* __restrict__ ai,
    const float* __restrict__ hr, const float* __restrict__ hi, float* __restrict__ h_o)
{
  const int blk = blockIdx.x;             // 0..127
  const int b = blk >> 6, d = blk & 63;
  const int lane = threadIdx.x;           // 0..63
  const size_t base = (size_t)b * LSEQ * DT + d;
  const int i0 = lane * 8;

  float a_r[8], a_i[8], b_r[8], b_i[8];
#pragma unroll
  for (int e = 0; e < 8; ++e) {
    int i = i0 + e;
    a_r[e] = ar[base + (size_t)i * DT];
    a_i[e] = ai[base + (size_t)i * DT];
    if (i >= 2)      { b_r[e] = u[base + (size_t)(i - 2) * DT]; b_i[e] = 0.f; }
    else if (i == 1) { b_r[e] = hr[d]; b_i[e] = hi[d]; }
    else             { b_r[e] = 0.f;   b_i[e] = 0.f; }
  }

  float Ar = 1.f, Ai = 0.f, Br = 0.f, Bi = 0.f;
#pragma unroll
  for (int e = 0; e < 8; ++e) {
    float nBr = fmaf(Ar, b_r[e], fmaf(-Ai, b_i[e], Br));
    float nBi = fmaf(Ar, b_i[e], fmaf( Ai, b_r[e], Bi));
    float nAr = Ar * a_r[e] - Ai * a_i[e];
    float nAi = Ar * a_i[e] + Ai * a_r[e];
    Ar = nAr; Ai = nAi; Br = nBr; Bi = nBi;
  }

#pragma unroll
  for (int dlt = 1; dlt < 64; dlt <<= 1) {
    float Ar2 = __shfl_down(Ar, dlt, 64);
    float Ai2 = __shfl_down(Ai, dlt, 64);
    float Br2 = __shfl_down(Br, dlt, 64);
    float Bi2 = __shfl_down(Bi, dlt, 64);
    if (lane + dlt < 64) {
      float nAr = Ar * Ar2 - Ai * Ai2;
      float nAi = Ar * Ai2 + Ai * Ar2;
      float nBr = fmaf(Ar, Br2, fmaf(-Ai, Bi2, Br));
      float nBi = fmaf(Ar, Bi2, fmaf( Ai, Br2, Bi));
      Ar = nAr; Ai = nAi; Br = nBr; Bi = nBi;
    }
  }

  float A1r = __shfl_down(Ar, 1, 64), A1i = __shfl_down(Ai, 1, 64);
  float B1r = __shfl_down(Br, 1, 64), B1i = __shfl_down(Bi, 1, 64);
  if (lane == 63) { A1r = 1.f; A1i = 0.f; B1r = 0.f; B1i = 0.f; }
  const float r512 = u[base + (size_t)(LSEQ - 2) * DT];
  float rr = fmaf(A1r, r512, B1r);
  float ri = fmaf(A1i, r512, B1i);

  const float uL = u[base + (size_t)(LSEQ - 1) * DT];
#pragma unroll
  for (int e = 7; e >= 0; --e) {
    int i = i0 + e;
    float nr = fmaf(a_r[e], rr, fmaf(-a_i[e], ri, b_r[e]));
    float ni = fmaf(a_r[e], ri, fmaf( a_i[e], rr, b_i[e]));
    rr = nr; ri = ni;
    float outv = rr;
    if (i == LSEQ - 1) outv += uL;
    h_o[base + (size_t)i * DT] = outv;
  }
}

// ---------------- k_tail: mid + LN2 + ffn1 + ffn2, row-band fused --------------------
// 64 blocks x 1024 thr (16 waves). Band = 16 rows (mt). Phases:
//  0: hy -> LDS hi/lo           1: mid GEMM (bf16x3) -> x2s LDS
//  2: LN2 -> xn2 LDS            3: ffn1 (16x16x32, K=512) -> h1s global (frag layout)
//  4: ffn2 (K=2048) -> out = acc + b2 + x2s
__global__ __launch_bounds__(1024) void k_tail(
    const float* __restrict__ h, const float* __restrict__ y,
    const float* __restrict__ low, const float* __restrict__ lob,
    const float* __restrict__ x, const float* __restrict__ g2,
    const float* __restrict__ be2,
    const float* __restrict__ b1, const float* __restrict__ b2,
    const u16* __restrict__ w1s, const u16* __restrict__ w2s,
    u16* __restrict__ h1s, float* __restrict__ out)
{
  __shared__ __align__(16) u16 hyh[16][80];
  __shared__ __align__(16) u16 hyl[16][80];
  __shared__ float x2s[16][520];
  __shared__ __align__(16) u16 xn2[16][520];
  const int tid = threadIdx.x;
  const int wv = tid >> 6, lane = tid & 63;
  const int lr = lane & 15, lk = lane >> 4;
  const int mt = blockIdx.x;

  {                                            // phase 0: hy hi/lo
    int r = tid >> 6, d = tid & 63;
    int row = mt * 16 + r;
    float v = h[row * DT + d] * y[row * DT + d];
    u16 hh, ll; splitbf(v, hh, ll);
    hyh[r][d] = hh; hyl[r][d] = ll;
  }
  __syncthreads();

#pragma unroll
  for (int t = 0; t < 2; ++t) {                // phase 1: mid tiles nt = wv*2+t
    const int nt = wv * 2 + t;
    const float* brow = low + (size_t)(nt * 16 + lr) * DT;
    f32x4 acc = {};
#pragma unroll
    for (int ks = 0; ks < 2; ++ks) {
      short8 ah = *(const short8*)&hyh[lr][ks * 32 + lk * 8];
      short8 al = *(const short8*)&hyl[lr][ks * 32 + lk * 8];
      short8 bh, bl;
      split8(brow + ks * 32 + lk * 8, bh, bl);
      acc = __builtin_amdgcn_mfma_f32_16x16x32_bf16(ah, bh, acc, 0, 0, 0);
      acc = __builtin_amdgcn_mfma_f32_16x16x32_bf16(ah, bl, acc, 0, 0, 0);
      acc = __builtin_amdgcn_mfma_f32_16x16x32_bf16(al, bh, acc, 0, 0, 0);
    }
    const int c = nt * 16 + lr;
#pragma unroll
    for (int j = 0; j < 4; ++j) {
      int rl = lk * 4 + j;
      int row = mt * 16 + rl;
      x2s[rl][c] = acc[j] + lob[c] + x[(size_t)row * DMODEL + c];
    }
  }
  __syncthreads();

  {                                            // phase 2: LN2, row wv -> xn2 LDS
    const int r = wv;
    float v[8]; float s = 0.f;
#pragma unroll
    for (int j = 0; j < 8; ++j) { v[j] = x2s[r][lane + 64 * j]; s += v[j]; }
    s = wave_sum(s);
    const float mu = s * (1.f / 512.f);
    float q = 0.f;
#pragma unroll
    for (int j = 0; j < 8; ++j) { float dd = v[j] - mu; q += dd * dd; }
    q = wave_sum(q);
    const float rstd = rsqrtf(q * (1.f / 512.f) + 1e-5f);
#pragma unroll
    for (int j = 0; j < 8; ++j) {
      int idx = lane + 64 * j;
      xn2[r][idx] = f2bf((v[j] - mu) * rstd * g2[idx] + be2[idx]);
    }
  }
  __syncthreads();

  {                                            // phase 3: ffn1, tiles t = wv*8+tt
#pragma unroll
    for (int tt = 0; tt < 8; ++tt) {
      const int t = wv * 8 + tt;               // out-col tile 0..127
      const u16* b = w1s + t * 8192 + lane * 8;
      f32x4 acc = {};
#pragma unroll
      for (int kb = 0; kb < 16; ++kb) {
        short8 af = *(const short8*)&xn2[lr][kb * 32 + lk * 8];
        short8 bf = *(const short8*)(b + kb * 512);
        acc = __builtin_amdgcn_mfma_f32_16x16x32_bf16(af, bf, acc, 0, 0, 0);
      }
      const int col = t * 16 + lr;
      const float bb = b1[col];
      const int kb2 = col >> 5, hi2 = (col & 31) >> 3, e2 = col & 7;
#pragma unroll
      for (int j = 0; j < 4; ++j) {
        int row16 = lk * 4 + j;
        float v = acc[j] + bb;
        v = v / (1.f + expf(-v));              // silu
        h1s[mt * 32768 + kb2 * 512 + (row16 + 16 * hi2) * 8 + e2] = f2bf(v);
      }
    }
  }
  __syncthreads();                             // drains vmcnt -> h1s visible in-block

  {                                            // phase 4: ffn2, tiles t2 = wv*2+tt
#pragma unroll
    for (int tt = 0; tt < 2; ++tt) {
      const int t2 = wv * 2 + tt;              // out-col tile 0..31
      const u16* a = h1s + mt * 32768 + lane * 8;
      const u16* b = w2s + t2 * 32768 + lane * 8;
      f32x4 acc = {};
      for (int kb = 0; kb < 64; ++kb) {
        short8 af = *(const short8*)(a + kb * 512);
        short8 bf = *(const short8*)(b + kb * 512);
        acc = __builtin_amdgcn_mfma_f32_16x16x32_bf16(af, bf, acc, 0, 0, 0);
      }
      const int col = t2 * 16 + lr;
      const float bb = b2[col];
#pragma unroll
      for (int j = 0; j < 4; ++j) {
        int row16 = lk * 4 + j;
        int row = mt * 16 + row16;
        out[(size_t)row * DMODEL + col] = acc[j] + bb + x2s[row16][col];
      }
    }
  }
}

// ---------------- launch -------------------------------------------------------------
extern "C" void kernel_launch(void* const* d_in, const int* in_sizes, int n_in,
                              void* d_out, int out_size, void* d_ws, size_t ws_size,
                              hipStream_t stream) {
  const float* x    = (const float*)d_in[0];
  const float* ln1g = (const float*)d_in[1];
  const float* ln1b = (const float*)d_in[2];
  const float* fcw  = (const float*)d_in[3];
  const float* fcb  = (const float*)d_in[4];
  const float* liw  = (const float*)d_in[5];
  const float* lib  = (const float*)d_in[6];
  const float* wa   = (const float*)d_in[7];
  const float* hidr = (const float*)d_in[8];
  const float* hidi = (const float*)d_in[9];
  const float* low  = (const float*)d_in[10];
  const float* lob  = (const float*)d_in[11];
  const float* ln2g = (const float*)d_in[12];
  const float* ln2b = (const float*)d_in[13];
  const float* w1   = (const float*)d_in[14];
  const float* b1   = (const float*)d_in[15];
  const float* w2   = (const float*)d_in[16];
  const float* b2   = (const float*)d_in[17];
  float* out = (float*)d_out;
  float* ws  = (float*)d_ws;

  float* y_   = ws;                            // 65536
  float* u_   = y_  + 65536;
  float* ar_  = u_  + 65536;
  float* ai_  = ar_ + 65536;
  float* h_   = ai_ + 65536;
  u16* p = (u16*)(h_ + 65536);
  u16* h1s  = p;            p += 2097152;      // 64 blocks x 32768 (16x16-frag)
  u16* w1s  = p;            p += 1048576;      // 16x16-frag swizzled
  u16* w2s  = p;            p += 1048576;      // 16x16-frag swizzled

  k_fa<<<320, 512, 0, stream>>>(x, ln1g, ln1b, fcw, liw, wa, fcb, lib, w1, w2,
                                y_, u_, ar_, ai_, w1s, w2s);
  k_scan2<<<128, 64, 0, stream>>>(u_, ar_, ai_, hidr, hidi, h_);
  k_tail<<<64, 1024, 0, stream>>>(h_, y_, low, lob, x, ln2g, ln2b, b1, b2,
                                  w1s, w2s, h1s, out);
}

// Round 14
// 53.408 us; speedup vs baseline: 1.7053x; 1.7053x over previous
//
#include <hip/hip_runtime.h>
#include <math.h>

#define LSEQ 512
#define DMODEL 512
#define DT 64
#define DFF 2048

typedef unsigned short u16;
typedef __attribute__((ext_vector_type(8))) short short8;
typedef __attribute__((ext_vector_type(4))) float f32x4;
typedef __attribute__((ext_vector_type(16))) float f32x16;

__device__ __forceinline__ float wave_sum(float v) {
#pragma unroll
  for (int o = 32; o > 0; o >>= 1) v += __shfl_xor(v, o, 64);
  return v;
}

__device__ __forceinline__ u16 f2bf(float f) {
  unsigned int u = __float_as_uint(f);
  u += 0x7fffu + ((u >> 16) & 1u);
  return (u16)(u >> 16);
}
__device__ __forceinline__ float bf2f(u16 h) {
  return __uint_as_float(((unsigned int)h) << 16);
}
__device__ __forceinline__ void splitbf(float f, u16& h, u16& l) {
  h = f2bf(f);
  l = f2bf(f - bf2f(h));
}
// load 8 fp32 and split into hi/lo bf16 fragments
__device__ __forceinline__ void split8(const float* __restrict__ p,
                                       short8& bh, short8& bl) {
  float4 a = *(const float4*)p;
  float4 b = *(const float4*)(p + 4);
  float vv[8] = {a.x, a.y, a.z, a.w, b.x, b.y, b.z, b.w};
#pragma unroll
  for (int e = 0; e < 8; ++e) {
    u16 h, l; splitbf(vv[e], h, l);
    bh[e] = (short)h; bl[e] = (short)l;
  }
}

// Layouts:
//  w1s: 16x16-frag for 16x16x32 MFMA: X[R][C] -> t=r/16, kb=c/32,
//       lane=(r%16)+16*((c%32)/8), e=c%8; flat = t*(C*16) + kb*512 + lane*8 + e
//  w2s/h1s: 32x32-frag for 32x32x16 MFMA: t=r/32, kb=c/16,
//       lane=(r%32)+32*((c%16)/8), e=c%8; flat = t*(C*32) + kb*512 + lane*8 + e

// ---------------- k_fa: blocks 0..63: LN1 + proj(fc+lin_in bf16x3) + au + a-map ------
//                  blocks 64..319: w1 -> 16x16-frag, w2 -> 32x32-frag bf16
__global__ __launch_bounds__(512) void k_fa(
    const float* __restrict__ x, const float* __restrict__ g1,
    const float* __restrict__ be1,
    const float* __restrict__ fcw, const float* __restrict__ liw,
    const float* __restrict__ wa,
    const float* __restrict__ fcb, const float* __restrict__ lib,
    const float* __restrict__ w1, const float* __restrict__ w2,
    float* __restrict__ y_o, float* __restrict__ u_o,
    float* __restrict__ ar_o, float* __restrict__ ai_o,
    u16* __restrict__ w1s, u16* __restrict__ w2s)
{
  const int blk = blockIdx.x;
  if (blk >= 64) {                           // ---- weight conversion ----
    for (int i = (blk - 64) * 512 + threadIdx.x; i < 524288; i += 131072) {
      if (i < 262144) {                      // w1 (2048 x 512) -> 16x16-frag
        int r = i >> 7, c0 = (i & 127) << 2;
        float4 v = ((const float4*)w1)[i];
        ushort4 o;
        o.x = f2bf(v.x); o.y = f2bf(v.y); o.z = f2bf(v.z); o.w = f2bf(v.w);
        int flat = (r >> 4) * 8192 + (c0 >> 5) * 512 +
                   ((r & 15) + 16 * ((c0 & 31) >> 3)) * 8 + (c0 & 7);
        *(ushort4*)(w1s + flat) = o;
      } else {                               // w2 (512 x 2048) -> 32x32-frag
        int ii = i - 262144;
        int r = ii >> 9, c0 = (ii & 511) << 2;
        float4 v = ((const float4*)w2)[ii];
        ushort4 o;
        o.x = f2bf(v.x); o.y = f2bf(v.y); o.z = f2bf(v.z); o.w = f2bf(v.w);
        int lane_s = (r & 31) + (((c0 & 15) >> 3) << 5);
        int flat = (r >> 5) * 65536 + (c0 >> 4) * 512 + lane_s * 8 + (c0 & 7);
        *(ushort4*)(w2s + flat) = o;
      }
    }
    return;
  }
  // ---- compute blocks: 16-row tile mt ----
  __shared__ __align__(16) u16 xsh[16][520];
  __shared__ __align__(16) u16 xsl[16][520];
  __shared__ __align__(16) u16 ush[16][80];
  __shared__ __align__(16) u16 usl[16][80];
  const int tid = threadIdx.x;
  const int wv = tid >> 6, lane = tid & 63;
  const int lr = lane & 15, lk = lane >> 4;
  const int mt = blk;

#pragma unroll
  for (int rr = 0; rr < 2; ++rr) {           // LN1, 16 rows
    const int r = wv * 2 + rr;
    const int row = mt * 16 + r;
    const float* xr = x + (size_t)row * DMODEL;
    float v[8]; float s = 0.f;
#pragma unroll
    for (int j = 0; j < 8; ++j) { v[j] = xr[lane + 64 * j]; s += v[j]; }
    s = wave_sum(s);
    const float mu = s * (1.f / 512.f);
    float q = 0.f;
#pragma unroll
    for (int j = 0; j < 8; ++j) { float dd = v[j] - mu; q += dd * dd; }
    q = wave_sum(q);
    const float rstd = rsqrtf(q * (1.f / 512.f) + 1e-5f);
#pragma unroll
    for (int j = 0; j < 8; ++j) {
      int idx = lane + 64 * j;
      float o = (v[j] - mu) * rstd * g1[idx] + be1[idx];
      u16 h, l; splitbf(o, h, l);
      xsh[r][idx] = h;
      xsl[r][idx] = l;
    }
  }
  __syncthreads();

  const int c = wv * 16 + lr;
  {  // proj tile, K=512, bf16x3; B fp32 split on the fly
    const float* brow = (c < DT) ? (fcw + (size_t)c * DMODEL)
                                 : (liw + (size_t)(c - DT) * DMODEL);
    f32x4 acc = {};
#pragma unroll 4
    for (int k = 0; k < DMODEL; k += 32) {
      short8 ah = *(const short8*)&xsh[lr][k + lk * 8];
      short8 al = *(const short8*)&xsl[lr][k + lk * 8];
      short8 bh, bl;
      split8(brow + k + lk * 8, bh, bl);
      acc = __builtin_amdgcn_mfma_f32_16x16x32_bf16(ah, bh, acc, 0, 0, 0);
      acc = __builtin_amdgcn_mfma_f32_16x16x32_bf16(ah, bl, acc, 0, 0, 0);
      acc = __builtin_amdgcn_mfma_f32_16x16x32_bf16(al, bh, acc, 0, 0, 0);
    }
#pragma unroll
    for (int j = 0; j < 4; ++j) {
      int rl = lk * 4 + j;
      int row = mt * 16 + rl;
      float v = acc[j];
      if (c < DT) {
        v += fcb[c];
        y_o[row * DT + c] = v / (1.f + expf(-v));        // silu gate (fp32)
      } else {
        int d = c - DT;
        v += lib[d];
        u_o[row * DT + d] = v;                           // fp32 for scan
        u16 h, l; splitbf(v, h, l);
        ush[rl][d] = h; usl[rl][d] = l;
      }
    }
  }
  __syncthreads();
  {  // au tile nt=wv over K=64, bf16x3; then a-map
    const float* warow = wa + (size_t)c * DT;
    f32x4 acc = {};
#pragma unroll
    for (int ks = 0; ks < 2; ++ks) {
      short8 ah = *(const short8*)&ush[lr][ks * 32 + lk * 8];
      short8 al = *(const short8*)&usl[lr][ks * 32 + lk * 8];
      short8 bh, bl;
      split8(warow + ks * 32 + lk * 8, bh, bl);
      acc = __builtin_amdgcn_mfma_f32_16x16x32_bf16(ah, bh, acc, 0, 0, 0);
      acc = __builtin_amdgcn_mfma_f32_16x16x32_bf16(ah, bl, acc, 0, 0, 0);
      acc = __builtin_amdgcn_mfma_f32_16x16x32_bf16(al, bh, acc, 0, 0, 0);
    }
#pragma unroll
    for (int j = 0; j < 4; ++j) {
      float v = acc[j];
      float p = __shfl_xor(v, 1, 64);
      float re = (lane & 1) ? p : v;
      float im = (lane & 1) ? v : p;
      float asq = re * re + im * im;
      float sc = rsqrtf(asq) * expf(-asq);
      int row = mt * 16 + lk * 4 + j;
      int d = c >> 1;
      if (lane & 1) ai_o[row * DT + d] = im * sc;
      else          ar_o[row * DT + d] = re * sc;
    }
  }
}

// ---------------- parallel backward affine scan (unchanged) --------------------------
__global__ __launch_bounds__(64) void k_scan2(
    const float* __restrict__ u, const float* __restrict__ ar, const float* __restrict__ ai,
    const float* __restrict__ hr, const float* __restrict__ hi, float* __restrict__ h_o)
{
  const int blk = blockIdx.x;             // 0..127
  const int b = blk >> 6, d = blk & 63;
  const int lane = threadIdx.x;           // 0..63
  const size_t base = (size_t)b * LSEQ * DT + d;
  const int i0 = lane * 8;

  float a_r[8], a_i[8], b_r[8], b_i[8];
#pragma unroll
  for (int e = 0; e < 8; ++e) {
    int i = i0 + e;
    a_r[e] = ar[base + (size_t)i * DT];
    a_i[e] = ai[base + (size_t)i * DT];
    if (i >= 2)      { b_r[e] = u[base + (size_t)(i - 2) * DT]; b_i[e] = 0.f; }
    else if (i == 1) { b_r[e] = hr[d]; b_i[e] = hi[d]; }
    else             { b_r[e] = 0.f;   b_i[e] = 0.f; }
  }

  float Ar = 1.f, Ai = 0.f, Br = 0.f, Bi = 0.f;
#pragma unroll
  for (int e = 0; e < 8; ++e) {
    float nBr = fmaf(Ar, b_r[e], fmaf(-Ai, b_i[e], Br));
    float nBi = fmaf(Ar, b_i[e], fmaf( Ai, b_r[e], Bi));
    float nAr = Ar * a_r[e] - Ai * a_i[e];
    float nAi = Ar * a_i[e] + Ai * a_r[e];
    Ar = nAr; Ai = nAi; Br = nBr; Bi = nBi;
  }

#pragma unroll
  for (int dlt = 1; dlt < 64; dlt <<= 1) {
    float Ar2 = __shfl_down(Ar, dlt, 64);
    float Ai2 = __shfl_down(Ai, dlt, 64);
    float Br2 = __shfl_down(Br, dlt, 64);
    float Bi2 = __shfl_down(Bi, dlt, 64);
    if (lane + dlt < 64) {
      float nAr = Ar * Ar2 - Ai * Ai2;
      float nAi = Ar * Ai2 + Ai * Ar2;
      float nBr = fmaf(Ar, Br2, fmaf(-Ai, Bi2, Br));
      float nBi = fmaf(Ar, Bi2, fmaf( Ai, Br2, Bi));
      Ar = nAr; Ai = nAi; Br = nBr; Bi = nBi;
    }
  }

  float A1r = __shfl_down(Ar, 1, 64), A1i = __shfl_down(Ai, 1, 64);
  float B1r = __shfl_down(Br, 1, 64), B1i = __shfl_down(Bi, 1, 64);
  if (lane == 63) { A1r = 1.f; A1i = 0.f; B1r = 0.f; B1i = 0.f; }
  const float r512 = u[base + (size_t)(LSEQ - 2) * DT];
  float rr = fmaf(A1r, r512, B1r);
  float ri = fmaf(A1i, r512, B1i);

  const float uL = u[base + (size_t)(LSEQ - 1) * DT];
#pragma unroll
  for (int e = 7; e >= 0; --e) {
    int i = i0 + e;
    float nr = fmaf(a_r[e], rr, fmaf(-a_i[e], ri, b_r[e]));
    float ni = fmaf(a_r[e], ri, fmaf( a_i[e], rr, b_i[e]));
    rr = nr; ri = ni;
    float outv = rr;
    if (i == LSEQ - 1) outv += uL;
    h_o[base + (size_t)i * DT] = outv;
  }
}

// ---------------- k_mfl: mid + LN2 + ffn1-chunk, 256 blocks x 512 thr ----------------
// Block = (mt 0..63, chunk 0..3). Phases 0-2 (mid bf16x3 -> x2s, LN2 -> xn2) are
// recomputed per chunk (cheap, fully parallel). Phase 3: ffn1 for 512-col chunk,
// h1 written in 32x32-frag layout for k_ffn2. x2 written to global by chunk 0 only.
__global__ __launch_bounds__(512) void k_mfl(
    const float* __restrict__ h, const float* __restrict__ y,
    const float* __restrict__ low, const float* __restrict__ lob,
    const float* __restrict__ x, const float* __restrict__ g2,
    const float* __restrict__ be2, const float* __restrict__ b1,
    const u16* __restrict__ w1s,
    float* __restrict__ x2_o, u16* __restrict__ h1s)
{
  __shared__ __align__(16) u16 hyh[16][80];
  __shared__ __align__(16) u16 hyl[16][80];
  __shared__ float x2s[16][520];
  __shared__ __align__(16) u16 xn2[16][520];
  const int tid = threadIdx.x;
  const int wv = tid >> 6, lane = tid & 63;
  const int lr = lane & 15, lk = lane >> 4;
  const int mt = blockIdx.x >> 2, chunk = blockIdx.x & 3;

#pragma unroll
  for (int it = 0; it < 2; ++it) {             // phase 0: hy hi/lo
    int idx = it * 512 + tid;
    int r = idx >> 6, d = idx & 63;
    int row = mt * 16 + r;
    float v = h[row * DT + d] * y[row * DT + d];
    u16 hh, ll; splitbf(v, hh, ll);
    hyh[r][d] = hh; hyl[r][d] = ll;
  }
  __syncthreads();

#pragma unroll
  for (int t = 0; t < 4; ++t) {                // phase 1: mid tiles nt = wv*4+t
    const int nt = wv * 4 + t;
    const float* brow = low + (size_t)(nt * 16 + lr) * DT;
    f32x4 acc = {};
#pragma unroll
    for (int ks = 0; ks < 2; ++ks) {
      short8 ah = *(const short8*)&hyh[lr][ks * 32 + lk * 8];
      short8 al = *(const short8*)&hyl[lr][ks * 32 + lk * 8];
      short8 bh, bl;
      split8(brow + ks * 32 + lk * 8, bh, bl);
      acc = __builtin_amdgcn_mfma_f32_16x16x32_bf16(ah, bh, acc, 0, 0, 0);
      acc = __builtin_amdgcn_mfma_f32_16x16x32_bf16(ah, bl, acc, 0, 0, 0);
      acc = __builtin_amdgcn_mfma_f32_16x16x32_bf16(al, bh, acc, 0, 0, 0);
    }
    const int c = nt * 16 + lr;
#pragma unroll
    for (int j = 0; j < 4; ++j) {
      int rl = lk * 4 + j;
      int row = mt * 16 + rl;
      float v = acc[j] + lob[c] + x[(size_t)row * DMODEL + c];
      x2s[rl][c] = v;
      if (chunk == 0) x2_o[(size_t)row * DMODEL + c] = v;
    }
  }
  __syncthreads();

#pragma unroll
  for (int rr = 0; rr < 2; ++rr) {             // phase 2: LN2, 2 rows/wave
    const int r = wv * 2 + rr;
    float v[8]; float s = 0.f;
#pragma unroll
    for (int j = 0; j < 8; ++j) { v[j] = x2s[r][lane + 64 * j]; s += v[j]; }
    s = wave_sum(s);
    const float mu = s * (1.f / 512.f);
    float q = 0.f;
#pragma unroll
    for (int j = 0; j < 8; ++j) { float dd = v[j] - mu; q += dd * dd; }
    q = wave_sum(q);
    const float rstd = rsqrtf(q * (1.f / 512.f) + 1e-5f);
#pragma unroll
    for (int j = 0; j < 8; ++j) {
      int idx = lane + 64 * j;
      xn2[r][idx] = f2bf((v[j] - mu) * rstd * g2[idx] + be2[idx]);
    }
  }
  __syncthreads();

  {                                            // phase 3: ffn1 col-chunk
    const int t32 = mt >> 1;
#pragma unroll
    for (int tt = 0; tt < 4; ++tt) {
      const int t = chunk * 32 + wv * 4 + tt;  // out-col tile 0..127
      const u16* b = w1s + t * 8192 + lane * 8;
      f32x4 acc = {};
#pragma unroll
      for (int kb = 0; kb < 16; ++kb) {
        short8 af = *(const short8*)&xn2[lr][kb * 32 + lk * 8];
        short8 bf = *(const short8*)(b + kb * 512);
        acc = __builtin_amdgcn_mfma_f32_16x16x32_bf16(af, bf, acc, 0, 0, 0);
      }
      const int col = t * 16 + lr;
      const float bb = b1[col];
#pragma unroll
      for (int j = 0; j < 4; ++j) {
        int row16 = lk * 4 + j;
        float v = acc[j] + bb;
        v = v / (1.f + expf(-v));              // silu
        int r32 = (mt & 1) * 16 + row16;
        int lane_s = r32 + 32 * (lr >> 3);
        h1s[t32 * 65536 + t * 512 + lane_s * 8 + (lr & 7)] = f2bf(v);
      }
    }
  }
}

// ---------------- k_ffn2: out = h1 @ w2^T + b2 + x2; 4-wave in-block split-K ---------
__global__ __launch_bounds__(256) void k_ffn2(
    const u16* __restrict__ As, const u16* __restrict__ Bs,
    const float* __restrict__ b2, const float* __restrict__ x2,
    float* __restrict__ out)
{
  __shared__ float red[4][16][64];
  const int w = threadIdx.x >> 6, lane = threadIdx.x & 63;
  const int mt = blockIdx.x, nt = blockIdx.y;
  const u16* a = As + mt * 65536 + w * 32 * 512 + lane * 8;
  const u16* b = Bs + nt * 65536 + w * 32 * 512 + lane * 8;
  f32x16 acc = {};
#pragma unroll 8
  for (int kb = 0; kb < 32; ++kb)
    acc = __builtin_amdgcn_mfma_f32_32x32x16_bf16(*(const short8*)(a + kb * 512),
                                                  *(const short8*)(b + kb * 512),
                                                  acc, 0, 0, 0);
#pragma unroll
  for (int r = 0; r < 16; ++r) red[w][r][lane] = acc[r];
  __syncthreads();
  for (int s = threadIdx.x; s < 1024; s += 256) {
    int r = s >> 6, l = s & 63;
    float v = red[0][r][l] + red[1][r][l] + red[2][r][l] + red[3][r][l];
    int row = mt * 32 + (r & 3) + 8 * (r >> 2) + 4 * (l >> 5);
    int col = nt * 32 + (l & 31);
    out[(size_t)row * DMODEL + col] =
        v + b2[col] + x2[(size_t)row * DMODEL + col];
  }
}

// ---------------- launch -------------------------------------------------------------
extern "C" void kernel_launch(void* const* d_in, const int* in_sizes, int n_in,
                              void* d_out, int out_size, void* d_ws, size_t ws_size,
                              hipStream_t stream) {
  const float* x    = (const float*)d_in[0];
  const float* ln1g = (const float*)d_in[1];
  const float* ln1b = (const float*)d_in[2];
  const float* fcw  = (const float*)d_in[3];
  const float* fcb  = (const float*)d_in[4];
  const float* liw  = (const float*)d_in[5];
  const float* lib  = (const float*)d_in[6];
  const float* wa   = (const float*)d_in[7];
  const float* hidr = (const float*)d_in[8];
  const float* hidi = (const float*)d_in[9];
  const float* low  = (const float*)d_in[10];
  const float* lob  = (const float*)d_in[11];
  const float* ln2g = (const float*)d_in[12];
  const float* ln2b = (const float*)d_in[13];
  const float* w1   = (const float*)d_in[14];
  const float* b1   = (const float*)d_in[15];
  const float* w2   = (const float*)d_in[16];
  const float* b2   = (const float*)d_in[17];
  float* out = (float*)d_out;
  float* ws  = (float*)d_ws;

  float* y_   = ws;                            // 65536
  float* u_   = y_  + 65536;
  float* ar_  = u_  + 65536;
  float* ai_  = ar_ + 65536;
  float* h_   = ai_ + 65536;
  float* x2_  = h_  + 65536;                   // 524288
  u16* p = (u16*)(x2_ + 524288);
  u16* h1s  = p;            p += 2097152;      // 32x32-frag
  u16* w1s  = p;            p += 1048576;      // 16x16-frag
  u16* w2s  = p;            p += 1048576;      // 32x32-frag

  k_fa<<<320, 512, 0, stream>>>(x, ln1g, ln1b, fcw, liw, wa, fcb, lib, w1, w2,
                                y_, u_, ar_, ai_, w1s, w2s);
  k_scan2<<<128, 64, 0, stream>>>(u_, ar_, ai_, hidr, hidi, h_);
  k_mfl<<<256, 512, 0, stream>>>(h_, y_, low, lob, x, ln2g, ln2b, b1,
                                 w1s, x2_, h1s);
  k_ffn2<<<dim3(32, 16), 256, 0, stream>>>(h1s, w2s, b2, x2_, out);
}